// Round 3
// baseline (607.508 us; speedup 1.0000x reference)
//
#include <hip/hip_runtime.h>
#include <hip/hip_bf16.h>

// Problem constants (match reference)
#define NNODES 100000
#define NEDGES 3200000
#define INDIM  512
#define HID    128
#define NCLS   64

// Bucketed CSR build
#define NBUCK  256
#define NPB    391                         // nodes per bucket; 256*391 = 100096
#define NCAP   (NBUCK * NPB)               // 100096
#define BCAP   16384                       // fixed padded capacity per bucket
#define CHUNK  8192
#define NCHUNKB ((NEDGES + CHUNK - 1) / CHUNK)   // 391 blocks

typedef __bf16 bf16x8 __attribute__((ext_vector_type(8)));
typedef float  f32x4  __attribute__((ext_vector_type(4)));

#define HPAD 136   // h0s row pad (272B stride; 68 words %32=4)

// ---------------------------------------------------------------------------
// Fused: blocks 0..390 = per-chunk bucket histogram (reserve runs);
//        block 391     = weight conversion into MFMA-FRAGMENT-PACKED order.
// W0P[((kk*8+t)*64+lane)*8 + j] = W0[(kk*32+(lane>>4)*8+j)*HID + t*16+(lane&15)]
// => each B-fragment load in the GEMM is a fully-coalesced contiguous 1KB
//    wave-load (16B/lane), per-kk working set 8KB (L1-resident).
// ---------------------------------------------------------------------------
__global__ __launch_bounds__(256)
void k_count_wcvt(const int* __restrict__ dst, int* __restrict__ gcnt,
                  int* __restrict__ my_base,
                  const float* __restrict__ W0, const float* __restrict__ W1,
                  __bf16* __restrict__ W0P, __bf16* __restrict__ W1P) {
  const int t = threadIdx.x;
  if (blockIdx.x == NCHUNKB) {
    for (int i = t; i < 65536; i += 256) {      // W0 [512][128] -> packed
      const int c = i >> 3, j = i & 7;
      const int ln = c & 63, tt = (c >> 6) & 7, kk = c >> 9;
      const int row = tt * 16 + (ln & 15);
      const int k   = kk * 32 + (ln >> 4) * 8 + j;
      W0P[i] = (__bf16)W0[k * HID + row];
    }
    for (int i = t; i < 8192; i += 256) {       // W1 [128][64] -> packed
      const int c = i >> 3, j = i & 7;
      const int ln = c & 63, tt = (c >> 6) & 3, kk = c >> 8;
      const int row = tt * 16 + (ln & 15);
      const int k   = kk * 32 + (ln >> 4) * 8 + j;
      W1P[i] = (__bf16)W1[k * NCLS + row];
    }
    return;
  }
  __shared__ int cnt[NBUCK];
  cnt[t] = 0;
  __syncthreads();
  const int base = blockIdx.x * CHUNK;
#pragma unroll
  for (int j = 0; j < CHUNK / 1024; ++j) {
    const int e = base + (j * 256 + t) * 4;
    if (e < NEDGES) {                           // NEDGES%4==0 => full int4 ok
      const int4 d = *(const int4*)&dst[e];
      atomicAdd(&cnt[(unsigned)d.x / NPB], 1);
      atomicAdd(&cnt[(unsigned)d.y / NPB], 1);
      atomicAdd(&cnt[(unsigned)d.z / NPB], 1);
      atomicAdd(&cnt[(unsigned)d.w / NPB], 1);
    }
  }
  __syncthreads();
  my_base[blockIdx.x * NBUCK + t] = atomicAdd(&gcnt[t], cnt[t]);
}

// ---------------------------------------------------------------------------
// Exclusive scan of bucket totals -> bsv segment bases.
// ---------------------------------------------------------------------------
__global__ void kA_bscan(const int* __restrict__ gcnt, int* __restrict__ bbase) {
  __shared__ int s[256];
  const int t = threadIdx.x;
  const int v = gcnt[t];
  s[t] = v;
  __syncthreads();
  for (int off = 1; off < 256; off <<= 1) {
    int x = (t >= off) ? s[t - off] : 0;
    __syncthreads();
    s[t] += x;
    __syncthreads();
  }
  bbase[t] = s[t] - v;
  if (t == 255) bbase[256] = s[255];            // == NEDGES
}

// ---------------------------------------------------------------------------
// Fused dispatch: blocks 0..390 = edge scatter into bucket runs;
// blocks 391.. = dense GEMM h1 = relu(X@W0)@W1 (bf16 MFMA).
// B fragments come from FRAGMENT-PACKED W0P/W1P in global: every load is a
// contiguous coalesced 1KB wave-load, 8KB/kk hot set -> L1 hits. No weight
// LDS, no barriers in the GEMM branch; LDS is only the 17.4KB h0s relay
// (per-wave private stripes) -> ~8 blocks/CU (thread cap), vs 1 with the
// 133KB full-W0T LDS variant (rounds 0/2: blocks/CU was the binding limit).
// ---------------------------------------------------------------------------
__global__ __launch_bounds__(256, 8)
void k_scatter_gemm(const int* __restrict__ dst, const int* __restrict__ src,
                    const float* __restrict__ val, const int* __restrict__ bbase,
                    const int* __restrict__ my_base, int2* __restrict__ bsv,
                    const float* __restrict__ feat, const __bf16* __restrict__ W0P,
                    const __bf16* __restrict__ W1P, __bf16* __restrict__ h1b) {
  __shared__ __align__(16) char smem[64 * HPAD * 2];   // 17,408 B
  const int tid = threadIdx.x;

  if (blockIdx.x < NCHUNKB) {
    // ---------------- scatter branch ----------------
    int* cur = (int*)smem;
    cur[tid] = bbase[tid] + my_base[blockIdx.x * NBUCK + tid];
    __syncthreads();
    const int base = blockIdx.x * CHUNK;
#pragma unroll
    for (int j = 0; j < CHUNK / 1024; ++j) {
      const int e = base + (j * 256 + tid) * 4;
      if (e < NEDGES) {
        const int4   d  = *(const int4*)&dst[e];
        const int4   sc = *(const int4*)&src[e];
        const float4 vv = *(const float4*)&val[e];
        int p, b, ld;
        b = (unsigned)d.x / NPB; ld = d.x - b * NPB;
        p = atomicAdd(&cur[b], 1);
        bsv[p] = make_int2(sc.x | (ld << 17), __float_as_int(vv.x));
        b = (unsigned)d.y / NPB; ld = d.y - b * NPB;
        p = atomicAdd(&cur[b], 1);
        bsv[p] = make_int2(sc.y | (ld << 17), __float_as_int(vv.y));
        b = (unsigned)d.z / NPB; ld = d.z - b * NPB;
        p = atomicAdd(&cur[b], 1);
        bsv[p] = make_int2(sc.z | (ld << 17), __float_as_int(vv.z));
        b = (unsigned)d.w / NPB; ld = d.w - b * NPB;
        p = atomicAdd(&cur[b], 1);
        bsv[p] = make_int2(sc.w | (ld << 17), __float_as_int(vv.w));
      }
    }
    return;
  }

  // ---------------- gemm branch (4 waves, 64 rows) ----------------
  __bf16* h0s = (__bf16*)smem;                 // [64][HPAD] per-wave stripes

  const int wave = tid >> 6;
  const int lane = tid & 63;
  const int q    = lane >> 4;
  const int l16  = lane & 15;
  const int rb   = (blockIdx.x - NCHUNKB) * 64;

  int row = rb + wave * 16 + l16;
  if (row >= NNODES) row = NNODES - 1;          // clamped loads; stores guarded
  const float* __restrict__ arow = feat + (size_t)row * INDIM;

  f32x4 acc[8];
#pragma unroll
  for (int t = 0; t < 8; ++t) acc[t] = (f32x4){0.f, 0.f, 0.f, 0.f};

#pragma unroll 4
  for (int kk = 0; kk < INDIM / 32; ++kk) {
    const int k0 = kk * 32;
    const float4 a0 = *(const float4*)&arow[k0 + q * 8];
    const float4 a1 = *(const float4*)&arow[k0 + q * 8 + 4];
    bf16x8 aF;
    aF[0] = (__bf16)a0.x; aF[1] = (__bf16)a0.y; aF[2] = (__bf16)a0.z; aF[3] = (__bf16)a0.w;
    aF[4] = (__bf16)a1.x; aF[5] = (__bf16)a1.y; aF[6] = (__bf16)a1.z; aF[7] = (__bf16)a1.w;
#pragma unroll
    for (int t = 0; t < 8; ++t) {
      const bf16x8 bF = *(const bf16x8*)&W0P[(size_t)(((kk * 8 + t) * 64 + lane) * 8)];
      acc[t] = __builtin_amdgcn_mfma_f32_16x16x32_bf16(aF, bF, acc[t], 0, 0, 0);
    }
  }

  // ReLU + cvt -> h0s in A-operand layout (C/D: row=q*4+j, col=l16).
  // No barriers: each wave writes and reads only its own 16-row stripe.
#pragma unroll
  for (int t = 0; t < 8; ++t) {
#pragma unroll
    for (int j = 0; j < 4; ++j) {
      float v = acc[t][j];
      v = v > 0.f ? v : 0.f;
      h0s[(wave * 16 + q * 4 + j) * HPAD + t * 16 + l16] = (__bf16)v;
    }
  }

  f32x4 acc2[4];
#pragma unroll
  for (int t = 0; t < 4; ++t) acc2[t] = (f32x4){0.f, 0.f, 0.f, 0.f};
#pragma unroll
  for (int kk = 0; kk < HID / 32; ++kk) {
    const bf16x8 aF = *(const bf16x8*)&h0s[(wave * 16 + l16) * HPAD + kk * 32 + q * 8];
#pragma unroll
    for (int t = 0; t < 4; ++t) {
      const bf16x8 bF = *(const bf16x8*)&W1P[(size_t)(((kk * 4 + t) * 64 + lane) * 8)];
      acc2[t] = __builtin_amdgcn_mfma_f32_16x16x32_bf16(aF, bF, acc2[t], 0, 0, 0);
    }
  }

#pragma unroll
  for (int t = 0; t < 4; ++t) {
#pragma unroll
    for (int j = 0; j < 4; ++j) {
      const int grow = rb + wave * 16 + q * 4 + j;
      if (grow < NNODES)
        h1b[(size_t)grow * NCLS + t * 16 + l16] = (__bf16)acc2[t][j];
    }
  }
}

// ---------------------------------------------------------------------------
// Per-bucket CSR fill: degree histogram + padded scan (pad to 8) in LDS,
// rowinfo[w] = {base, pdeg}; writes confined to a 128KB region per block.
// ---------------------------------------------------------------------------
__global__ __launch_bounds__(256)
void kB3(const int2* __restrict__ bsv, const int* __restrict__ bbase,
         int2* __restrict__ rowinfo, int2* __restrict__ ecsr) {
  __shared__ int dl[NPB];
  __shared__ int cur[NPB];
  __shared__ int s[256];
  const int t = threadIdx.x;
  const int b = blockIdx.x;
  const int nb = b * NPB;
  for (int i = t; i < NPB; i += 256) dl[i] = 0;
  __syncthreads();
  const int beg = bbase[b], end = bbase[b + 1];
  for (int e = beg + t; e < end; e += 256)
    atomicAdd(&dl[((unsigned)bsv[e].x) >> 17], 1);
  __syncthreads();
  const int i0 = t * 2, i1 = t * 2 + 1;
  const int d0 = (i0 < NPB) ? dl[i0] : 0;
  const int d1 = (i1 < NPB) ? dl[i1] : 0;
  const int p0 = (d0 + 7) & ~7, p1 = (d1 + 7) & ~7;
  const int tsum = p0 + p1;
  s[t] = tsum;
  __syncthreads();
  for (int off = 1; off < 256; off <<= 1) {
    int x = (t >= off) ? s[t - off] : 0;
    __syncthreads();
    s[t] += x;
    __syncthreads();
  }
  const int excl = s[t] - tsum;
  const int gb = b * BCAP;
  const int2 z2 = make_int2(0, 0);
  if (i0 < NPB) {
    const int c = gb + excl;
    cur[i0] = c;
    if (nb + i0 < NNODES) rowinfo[nb + i0] = make_int2(c, p0);
    for (int k = d0; k < p0; ++k) ecsr[c + k] = z2;   // zero padding entries
  }
  if (i1 < NPB) {
    const int c = gb + excl + p0;
    cur[i1] = c;
    if (nb + i1 < NNODES) rowinfo[nb + i1] = make_int2(c, p1);
    for (int k = d1; k < p1; ++k) ecsr[c + k] = z2;
  }
  __syncthreads();
  for (int e = beg + t; e < end; e += 256) {
    const int2 sv = bsv[e];
    const int ld = ((unsigned)sv.x) >> 17;
    const int p = atomicAdd(&cur[ld], 1);             // LDS atomic
    ecsr[p] = make_int2(sv.x & 0x1FFFF, sv.y);
  }
}

// ---------------------------------------------------------------------------
// SpMM gather: one wave per dst row, lane = output column. Degree padded
// to 8 -> 8 independent 128B line-gathers in flight per iteration.
// ---------------------------------------------------------------------------
template <typename OUT_T>
__global__ __launch_bounds__(256, 8)
void k_spmm(const int2* __restrict__ rowinfo, const int2* __restrict__ ecsr,
            const __bf16* __restrict__ x, OUT_T* __restrict__ y) {
  const int wl   = (blockIdx.x * 256 + threadIdx.x) >> 6;
  const int w    = __builtin_amdgcn_readfirstlane(wl);   // 25000*4 waves = NNODES
  const int lane = threadIdx.x & 63;
  const int2 ri  = rowinfo[w];                           // {base, pdeg}
  const int base = ri.x, pdeg = ri.y;
  float acc = 0.f;
  for (int j = 0; j < pdeg; j += 8) {
    const int4 m0 = *(const int4*)&ecsr[base + j];
    const int4 m1 = *(const int4*)&ecsr[base + j + 2];
    const int4 m2 = *(const int4*)&ecsr[base + j + 4];
    const int4 m3 = *(const int4*)&ecsr[base + j + 6];
    const float x0 = (float)x[(size_t)m0.x * NCLS + lane];
    const float x1 = (float)x[(size_t)m0.z * NCLS + lane];
    const float x2 = (float)x[(size_t)m1.x * NCLS + lane];
    const float x3 = (float)x[(size_t)m1.z * NCLS + lane];
    const float x4 = (float)x[(size_t)m2.x * NCLS + lane];
    const float x5 = (float)x[(size_t)m2.z * NCLS + lane];
    const float x6 = (float)x[(size_t)m3.x * NCLS + lane];
    const float x7 = (float)x[(size_t)m3.z * NCLS + lane];
    acc += __int_as_float(m0.y) * x0;
    acc += __int_as_float(m0.w) * x1;
    acc += __int_as_float(m1.y) * x2;
    acc += __int_as_float(m1.w) * x3;
    acc += __int_as_float(m2.y) * x4;
    acc += __int_as_float(m2.w) * x5;
    acc += __int_as_float(m3.y) * x6;
    acc += __int_as_float(m3.w) * x7;
  }
  y[(size_t)w * NCLS + lane] = (OUT_T)acc;
}

// ---------------------------------------------------------------------------
extern "C" void kernel_launch(void* const* d_in, const int* in_sizes, int n_in,
                              void* d_out, int out_size, void* d_ws, size_t ws_size,
                              hipStream_t stream) {
  const float* feat = (const float*)d_in[0];
  const float* W0   = (const float*)d_in[1];
  const float* W1   = (const float*)d_in[2];
  const float* eval = (const float*)d_in[3];
  const int*   esrc = (const int*)d_in[4];
  const int*   edst = (const int*)d_in[5];
  float* out = (float*)d_out;

  // Workspace (~60.5 MB). bsv lives in d_out (exactly NEDGES int2 = 25.6 MB,
  // dead after kB3; final spmm overwrites d_out).
  char* p = (char*)d_ws;
  int2*   ecsr    = (int2*)p;   p += (size_t)NBUCK * BCAP * 8;  // 33,554,432
  int2*   rowinfo = (int2*)p;   p += (size_t)NCAP * 8;          // 800,768
  int*    my_base = (int*)p;    p += 400384;
  int*    gcnt    = (int*)p;    p += 1024;
  int*    bbase   = (int*)p;    p += 2048;
  __bf16* W0P     = (__bf16*)p; p += 131072;
  __bf16* W1P     = (__bf16*)p; p += 16384;
  __bf16* h1b     = (__bf16*)p; p += 12800000;
  __bf16* h2b     = (__bf16*)p; p += 12800000;
  int2*   bsv     = (int2*)d_out;                               // 25,600,000

  hipMemsetAsync(gcnt, 0, NBUCK * sizeof(int), stream);
  k_count_wcvt <<<NCHUNKB + 1, 256, 0, stream>>>(edst, gcnt, my_base,
                                                 W0, W1, W0P, W1P);
  kA_bscan     <<<1, 256, 0, stream>>>(gcnt, bbase);
  k_scatter_gemm<<<NCHUNKB + (NNODES + 63) / 64, 256, 0, stream>>>(
      edst, esrc, eval, bbase, my_base, bsv, feat, W0P, W1P, h1b);
  kB3          <<<NBUCK, 256, 0, stream>>>(bsv, bbase, rowinfo, ecsr);

  k_spmm<__bf16><<<NNODES / 4, 256, 0, stream>>>(rowinfo, ecsr, h1b, h2b);
  k_spmm<float> <<<NNODES / 4, 256, 0, stream>>>(rowinfo, ecsr, h2b, out);

  (void)in_sizes; (void)n_in; (void)out_size; (void)ws_size;
}

// Round 4
// 589.093 us; speedup vs baseline: 1.0313x; 1.0313x over previous
//
#include <hip/hip_runtime.h>
#include <hip/hip_bf16.h>

// Problem constants (match reference)
#define NNODES 100000
#define NEDGES 3200000
#define INDIM  512
#define HID    128
#define NCLS   64

// Bucketed CSR build
#define NBUCK  256
#define NPB    391                         // nodes per bucket; 256*391 = 100096
#define NCAP   (NBUCK * NPB)               // 100096
#define BCAP   16384                       // fixed padded capacity per bucket
#define CHUNK  4096                        // smaller chunks -> 2x scatter blocks
#define NCHUNKB ((NEDGES + CHUNK - 1) / CHUNK)   // 782 blocks

typedef __bf16 bf16x8 __attribute__((ext_vector_type(8)));
typedef float  f32x4  __attribute__((ext_vector_type(4)));

#define HPAD 136   // h0s row pad (272B stride; 68 words %32=4)

// ---------------------------------------------------------------------------
// Fused: blocks 0..NCHUNKB-1 = per-chunk bucket histogram (reserve runs);
//        block NCHUNKB      = weight conversion into MFMA-FRAGMENT-PACKED order.
// W0P[((kk*8+t)*64+lane)*8 + j] = W0[(kk*32+(lane>>4)*8+j)*HID + t*16+(lane&15)]
// => each B-fragment load in the GEMM is a fully-coalesced contiguous 1KB
//    wave-load (16B/lane), per-kk working set 8KB.
// ---------------------------------------------------------------------------
__global__ __launch_bounds__(256)
void k_count_wcvt(const int* __restrict__ dst, int* __restrict__ gcnt,
                  int* __restrict__ my_base,
                  const float* __restrict__ W0, const float* __restrict__ W1,
                  __bf16* __restrict__ W0P, __bf16* __restrict__ W1P) {
  const int t = threadIdx.x;
  if (blockIdx.x == NCHUNKB) {
    for (int i = t; i < 65536; i += 256) {      // W0 [512][128] -> packed
      const int c = i >> 3, j = i & 7;
      const int ln = c & 63, tt = (c >> 6) & 7, kk = c >> 9;
      const int row = tt * 16 + (ln & 15);
      const int k   = kk * 32 + (ln >> 4) * 8 + j;
      W0P[i] = (__bf16)W0[k * HID + row];
    }
    for (int i = t; i < 8192; i += 256) {       // W1 [128][64] -> packed
      const int c = i >> 3, j = i & 7;
      const int ln = c & 63, tt = (c >> 6) & 3, kk = c >> 8;
      const int row = tt * 16 + (ln & 15);
      const int k   = kk * 32 + (ln >> 4) * 8 + j;
      W1P[i] = (__bf16)W1[k * NCLS + row];
    }
    return;
  }
  __shared__ int cnt[NBUCK];
  cnt[t] = 0;
  __syncthreads();
  const int base = blockIdx.x * CHUNK;
#pragma unroll
  for (int j = 0; j < CHUNK / 1024; ++j) {
    const int e = base + (j * 256 + t) * 4;
    if (e < NEDGES) {                           // NEDGES%4==0 => full int4 ok
      const int4 d = *(const int4*)&dst[e];
      atomicAdd(&cnt[(unsigned)d.x / NPB], 1);
      atomicAdd(&cnt[(unsigned)d.y / NPB], 1);
      atomicAdd(&cnt[(unsigned)d.z / NPB], 1);
      atomicAdd(&cnt[(unsigned)d.w / NPB], 1);
    }
  }
  __syncthreads();
  my_base[blockIdx.x * NBUCK + t] = atomicAdd(&gcnt[t], cnt[t]);
}

// ---------------------------------------------------------------------------
// Exclusive scan of bucket totals -> bsv segment bases.
// ---------------------------------------------------------------------------
__global__ void kA_bscan(const int* __restrict__ gcnt, int* __restrict__ bbase) {
  __shared__ int s[256];
  const int t = threadIdx.x;
  const int v = gcnt[t];
  s[t] = v;
  __syncthreads();
  for (int off = 1; off < 256; off <<= 1) {
    int x = (t >= off) ? s[t - off] : 0;
    __syncthreads();
    s[t] += x;
    __syncthreads();
  }
  bbase[t] = s[t] - v;
  if (t == 255) bbase[256] = s[255];            // == NEDGES
}

// ---------------------------------------------------------------------------
// Fused dispatch: blocks 0..NCHUNKB-1 = edge scatter into bucket runs;
// blocks NCHUNKB.. = dense GEMM h1 = relu(X@W0)@W1 (bf16 MFMA).
// B fragments from FRAGMENT-PACKED W0P/W1P in global: contiguous coalesced
// 1KB wave-loads. No weight LDS, no barriers in the GEMM branch; LDS is only
// the 17.4KB h0s relay. launch_bounds(256,4): 128-reg budget restores
// per-wave load batching (r3's (256,8) gave VGPR=32 -> serialized loads).
// ---------------------------------------------------------------------------
__global__ __launch_bounds__(256, 4)
void k_scatter_gemm(const int* __restrict__ dst, const int* __restrict__ src,
                    const float* __restrict__ val, const int* __restrict__ bbase,
                    const int* __restrict__ my_base, int2* __restrict__ bsv,
                    const float* __restrict__ feat, const __bf16* __restrict__ W0P,
                    const __bf16* __restrict__ W1P, __bf16* __restrict__ h1b) {
  __shared__ __align__(16) char smem[64 * HPAD * 2];   // 17,408 B
  const int tid = threadIdx.x;

  if (blockIdx.x < NCHUNKB) {
    // ---------------- scatter branch ----------------
    int* cur = (int*)smem;
    cur[tid] = bbase[tid] + my_base[blockIdx.x * NBUCK + tid];
    __syncthreads();
    const int base = blockIdx.x * CHUNK;
#pragma unroll
    for (int j = 0; j < CHUNK / 1024; ++j) {
      const int e = base + (j * 256 + tid) * 4;
      if (e < NEDGES) {
        const int4   d  = *(const int4*)&dst[e];
        const int4   sc = *(const int4*)&src[e];
        const float4 vv = *(const float4*)&val[e];
        int p, b, ld;
        b = (unsigned)d.x / NPB; ld = d.x - b * NPB;
        p = atomicAdd(&cur[b], 1);
        bsv[p] = make_int2(sc.x | (ld << 17), __float_as_int(vv.x));
        b = (unsigned)d.y / NPB; ld = d.y - b * NPB;
        p = atomicAdd(&cur[b], 1);
        bsv[p] = make_int2(sc.y | (ld << 17), __float_as_int(vv.y));
        b = (unsigned)d.z / NPB; ld = d.z - b * NPB;
        p = atomicAdd(&cur[b], 1);
        bsv[p] = make_int2(sc.z | (ld << 17), __float_as_int(vv.z));
        b = (unsigned)d.w / NPB; ld = d.w - b * NPB;
        p = atomicAdd(&cur[b], 1);
        bsv[p] = make_int2(sc.w | (ld << 17), __float_as_int(vv.w));
      }
    }
    return;
  }

  // ---------------- gemm branch (4 waves, 64 rows) ----------------
  __bf16* h0s = (__bf16*)smem;                 // [64][HPAD] per-wave stripes

  const int wave = tid >> 6;
  const int lane = tid & 63;
  const int q    = lane >> 4;
  const int l16  = lane & 15;
  const int rb   = (blockIdx.x - NCHUNKB) * 64;

  int row = rb + wave * 16 + l16;
  if (row >= NNODES) row = NNODES - 1;          // clamped loads; stores guarded
  const float* __restrict__ arow = feat + (size_t)row * INDIM;

  f32x4 acc[8];
#pragma unroll
  for (int t = 0; t < 8; ++t) acc[t] = (f32x4){0.f, 0.f, 0.f, 0.f};

#pragma unroll 4
  for (int kk = 0; kk < INDIM / 32; ++kk) {
    const int k0 = kk * 32;
    const float4 a0 = *(const float4*)&arow[k0 + q * 8];
    const float4 a1 = *(const float4*)&arow[k0 + q * 8 + 4];
    bf16x8 aF;
    aF[0] = (__bf16)a0.x; aF[1] = (__bf16)a0.y; aF[2] = (__bf16)a0.z; aF[3] = (__bf16)a0.w;
    aF[4] = (__bf16)a1.x; aF[5] = (__bf16)a1.y; aF[6] = (__bf16)a1.z; aF[7] = (__bf16)a1.w;
#pragma unroll
    for (int t = 0; t < 8; ++t) {
      const bf16x8 bF = *(const bf16x8*)&W0P[(size_t)(((kk * 8 + t) * 64 + lane) * 8)];
      acc[t] = __builtin_amdgcn_mfma_f32_16x16x32_bf16(aF, bF, acc[t], 0, 0, 0);
    }
  }

  // ReLU + cvt -> h0s in A-operand layout (C/D: row=q*4+j, col=l16).
  // No barriers: each wave writes and reads only its own 16-row stripe.
#pragma unroll
  for (int t = 0; t < 8; ++t) {
#pragma unroll
    for (int j = 0; j < 4; ++j) {
      float v = acc[t][j];
      v = v > 0.f ? v : 0.f;
      h0s[(wave * 16 + q * 4 + j) * HPAD + t * 16 + l16] = (__bf16)v;
    }
  }

  f32x4 acc2[4];
#pragma unroll
  for (int t = 0; t < 4; ++t) acc2[t] = (f32x4){0.f, 0.f, 0.f, 0.f};
#pragma unroll
  for (int kk = 0; kk < HID / 32; ++kk) {
    const bf16x8 aF = *(const bf16x8*)&h0s[(wave * 16 + l16) * HPAD + kk * 32 + q * 8];
#pragma unroll
    for (int t = 0; t < 4; ++t) {
      const bf16x8 bF = *(const bf16x8*)&W1P[(size_t)(((kk * 4 + t) * 64 + lane) * 8)];
      acc2[t] = __builtin_amdgcn_mfma_f32_16x16x32_bf16(aF, bF, acc2[t], 0, 0, 0);
    }
  }

#pragma unroll
  for (int t = 0; t < 4; ++t) {
#pragma unroll
    for (int j = 0; j < 4; ++j) {
      const int grow = rb + wave * 16 + q * 4 + j;
      if (grow < NNODES)
        h1b[(size_t)grow * NCLS + t * 16 + l16] = (__bf16)acc2[t][j];
    }
  }
}

// ---------------------------------------------------------------------------
// Per-bucket CSR fill, 512 threads (2x waves for the latency-bound histogram
// and placement phases): degree histogram + padded scan (pad to 8) in LDS,
// rowinfo[w] = {base, pdeg}; writes confined to a 128KB region per block.
// ---------------------------------------------------------------------------
__global__ __launch_bounds__(512)
void kB3(const int2* __restrict__ bsv, const int* __restrict__ bbase,
         int2* __restrict__ rowinfo, int2* __restrict__ ecsr) {
  __shared__ int dl[512];
  __shared__ int cur[NPB];
  __shared__ int s[512];
  const int t = threadIdx.x;
  const int b = blockIdx.x;
  const int nb = b * NPB;
  dl[t] = 0;
  __syncthreads();
  const int beg = bbase[b], end = bbase[b + 1];
  for (int e = beg + t; e < end; e += 512)
    atomicAdd(&dl[((unsigned)bsv[e].x) >> 17], 1);
  __syncthreads();
  const int d = (t < NPB) ? dl[t] : 0;
  const int pd = (d + 7) & ~7;
  s[t] = pd;
  __syncthreads();
  for (int off = 1; off < 512; off <<= 1) {
    int x = (t >= off) ? s[t - off] : 0;
    __syncthreads();
    s[t] += x;
    __syncthreads();
  }
  const int excl = s[t] - pd;
  const int gb = b * BCAP;
  const int2 z2 = make_int2(0, 0);
  if (t < NPB) {
    const int c = gb + excl;
    cur[t] = c;
    if (nb + t < NNODES) rowinfo[nb + t] = make_int2(c, pd);
    for (int k = d; k < pd; ++k) ecsr[c + k] = z2;    // zero padding entries
  }
  __syncthreads();
  for (int e = beg + t; e < end; e += 512) {
    const int2 sv = bsv[e];
    const int ld = ((unsigned)sv.x) >> 17;
    const int p = atomicAdd(&cur[ld], 1);             // LDS atomic
    ecsr[p] = make_int2(sv.x & 0x1FFFF, sv.y);
  }
}

// ---------------------------------------------------------------------------
// SpMM gather: one wave per dst row, lane = output column. Degree padded
// to 8 -> 8 independent 128B line-gathers in flight per iteration.
// ---------------------------------------------------------------------------
template <typename OUT_T>
__global__ __launch_bounds__(256, 8)
void k_spmm(const int2* __restrict__ rowinfo, const int2* __restrict__ ecsr,
            const __bf16* __restrict__ x, OUT_T* __restrict__ y) {
  const int wl   = (blockIdx.x * 256 + threadIdx.x) >> 6;
  const int w    = __builtin_amdgcn_readfirstlane(wl);   // 25000*4 waves = NNODES
  const int lane = threadIdx.x & 63;
  const int2 ri  = rowinfo[w];                           // {base, pdeg}
  const int base = ri.x, pdeg = ri.y;
  float acc = 0.f;
  for (int j = 0; j < pdeg; j += 8) {
    const int4 m0 = *(const int4*)&ecsr[base + j];
    const int4 m1 = *(const int4*)&ecsr[base + j + 2];
    const int4 m2 = *(const int4*)&ecsr[base + j + 4];
    const int4 m3 = *(const int4*)&ecsr[base + j + 6];
    const float x0 = (float)x[(size_t)m0.x * NCLS + lane];
    const float x1 = (float)x[(size_t)m0.z * NCLS + lane];
    const float x2 = (float)x[(size_t)m1.x * NCLS + lane];
    const float x3 = (float)x[(size_t)m1.z * NCLS + lane];
    const float x4 = (float)x[(size_t)m2.x * NCLS + lane];
    const float x5 = (float)x[(size_t)m2.z * NCLS + lane];
    const float x6 = (float)x[(size_t)m3.x * NCLS + lane];
    const float x7 = (float)x[(size_t)m3.z * NCLS + lane];
    acc += __int_as_float(m0.y) * x0;
    acc += __int_as_float(m0.w) * x1;
    acc += __int_as_float(m1.y) * x2;
    acc += __int_as_float(m1.w) * x3;
    acc += __int_as_float(m2.y) * x4;
    acc += __int_as_float(m2.w) * x5;
    acc += __int_as_float(m3.y) * x6;
    acc += __int_as_float(m3.w) * x7;
  }
  y[(size_t)w * NCLS + lane] = (OUT_T)acc;
}

// ---------------------------------------------------------------------------
extern "C" void kernel_launch(void* const* d_in, const int* in_sizes, int n_in,
                              void* d_out, int out_size, void* d_ws, size_t ws_size,
                              hipStream_t stream) {
  const float* feat = (const float*)d_in[0];
  const float* W0   = (const float*)d_in[1];
  const float* W1   = (const float*)d_in[2];
  const float* eval = (const float*)d_in[3];
  const int*   esrc = (const int*)d_in[4];
  const int*   edst = (const int*)d_in[5];
  float* out = (float*)d_out;

  // Workspace (~60.1 MB). bsv lives in d_out (exactly NEDGES int2 = 25.6 MB,
  // dead after kB3; final spmm overwrites d_out). my_base aliases h2b
  // (disjoint lifetimes: my_base dead after k_scatter_gemm; h2b first
  // written by spmm layer 1).
  char* p = (char*)d_ws;
  int2*   ecsr    = (int2*)p;   p += (size_t)NBUCK * BCAP * 8;  // 33,554,432
  int2*   rowinfo = (int2*)p;   p += (size_t)NCAP * 8;          // 800,768
  int*    gcnt    = (int*)p;    p += 1024;
  int*    bbase   = (int*)p;    p += 2048;
  __bf16* W0P     = (__bf16*)p; p += 131072;
  __bf16* W1P     = (__bf16*)p; p += 16384;
  __bf16* h1b     = (__bf16*)p; p += 12800000;
  __bf16* h2b     = (__bf16*)p; p += 12800000;
  int*    my_base = (int*)h2b;                                  // 800,768 alias
  int2*   bsv     = (int2*)d_out;                               // 25,600,000

  hipMemsetAsync(gcnt, 0, NBUCK * sizeof(int), stream);
  k_count_wcvt <<<NCHUNKB + 1, 256, 0, stream>>>(edst, gcnt, my_base,
                                                 W0, W1, W0P, W1P);
  kA_bscan     <<<1, 256, 0, stream>>>(gcnt, bbase);
  k_scatter_gemm<<<NCHUNKB + (NNODES + 63) / 64, 256, 0, stream>>>(
      edst, esrc, eval, bbase, my_base, bsv, feat, W0P, W1P, h1b);
  kB3          <<<NBUCK, 512, 0, stream>>>(bsv, bbase, rowinfo, ecsr);

  k_spmm<__bf16><<<NNODES / 4, 256, 0, stream>>>(rowinfo, ecsr, h1b, h2b);
  k_spmm<float> <<<NNODES / 4, 256, 0, stream>>>(rowinfo, ecsr, h2b, out);

  (void)in_sizes; (void)n_in; (void)out_size; (void)ws_size;
}

// Round 5
// 574.586 us; speedup vs baseline: 1.0573x; 1.0252x over previous
//
#include <hip/hip_runtime.h>
#include <hip/hip_bf16.h>

// Problem constants (match reference)
#define NNODES 100000
#define NEDGES 3200000
#define INDIM  512
#define HID    128
#define NCLS   64

// Bucketed CSR build
#define NBUCK  256
#define NPB    391                         // nodes per bucket; 256*391 = 100096
#define NCAP   (NBUCK * NPB)               // 100096
#define BCAP   16384                       // fixed padded capacity per bucket
#define CHUNK  4096                        // smaller chunks -> 2x scatter blocks
#define NCHUNKB ((NEDGES + CHUNK - 1) / CHUNK)   // 782 blocks

typedef __bf16 bf16x8 __attribute__((ext_vector_type(8)));
typedef __bf16 bf16x4 __attribute__((ext_vector_type(4)));
typedef float  f32x4  __attribute__((ext_vector_type(4)));

#define HPAD 136   // h0s row pad (272B stride; 68 words %32=4)

// ---------------------------------------------------------------------------
// Fused: blocks 0..NCHUNKB-1 = per-chunk bucket histogram (reserve runs);
//        block NCHUNKB      = weight conversion into MFMA-FRAGMENT-PACKED order.
// W0P[((kk*8+t)*64+lane)*8 + j] = W0[(kk*32+(lane>>4)*8+j)*HID + t*16+(lane&15)]
// => each B-fragment load in the GEMM is a fully-coalesced contiguous 1KB
//    wave-load (16B/lane), per-kk working set 8KB.
// ---------------------------------------------------------------------------
__global__ __launch_bounds__(256)
void k_count_wcvt(const int* __restrict__ dst, int* __restrict__ gcnt,
                  int* __restrict__ my_base,
                  const float* __restrict__ W0, const float* __restrict__ W1,
                  __bf16* __restrict__ W0P, __bf16* __restrict__ W1P) {
  const int t = threadIdx.x;
  if (blockIdx.x == NCHUNKB) {
    for (int i = t; i < 65536; i += 256) {      // W0 [512][128] -> packed
      const int c = i >> 3, j = i & 7;
      const int ln = c & 63, tt = (c >> 6) & 7, kk = c >> 9;
      const int row = tt * 16 + (ln & 15);
      const int k   = kk * 32 + (ln >> 4) * 8 + j;
      W0P[i] = (__bf16)W0[k * HID + row];
    }
    for (int i = t; i < 8192; i += 256) {       // W1 [128][64] -> packed
      const int c = i >> 3, j = i & 7;
      const int ln = c & 63, tt = (c >> 6) & 3, kk = c >> 8;
      const int row = tt * 16 + (ln & 15);
      const int k   = kk * 32 + (ln >> 4) * 8 + j;
      W1P[i] = (__bf16)W1[k * NCLS + row];
    }
    return;
  }
  __shared__ int cnt[NBUCK];
  cnt[t] = 0;
  __syncthreads();
  const int base = blockIdx.x * CHUNK;
#pragma unroll
  for (int j = 0; j < CHUNK / 1024; ++j) {
    const int e = base + (j * 256 + t) * 4;
    if (e < NEDGES) {                           // NEDGES%4==0 => full int4 ok
      const int4 d = *(const int4*)&dst[e];
      atomicAdd(&cnt[(unsigned)d.x / NPB], 1);
      atomicAdd(&cnt[(unsigned)d.y / NPB], 1);
      atomicAdd(&cnt[(unsigned)d.z / NPB], 1);
      atomicAdd(&cnt[(unsigned)d.w / NPB], 1);
    }
  }
  __syncthreads();
  my_base[blockIdx.x * NBUCK + t] = atomicAdd(&gcnt[t], cnt[t]);
}

// ---------------------------------------------------------------------------
// Exclusive scan of bucket totals -> bsv segment bases.
// ---------------------------------------------------------------------------
__global__ void kA_bscan(const int* __restrict__ gcnt, int* __restrict__ bbase) {
  __shared__ int s[256];
  const int t = threadIdx.x;
  const int v = gcnt[t];
  s[t] = v;
  __syncthreads();
  for (int off = 1; off < 256; off <<= 1) {
    int x = (t >= off) ? s[t - off] : 0;
    __syncthreads();
    s[t] += x;
    __syncthreads();
  }
  bbase[t] = s[t] - v;
  if (t == 255) bbase[256] = s[255];            // == NEDGES
}

// ---------------------------------------------------------------------------
// Fused dispatch: blocks 0..NCHUNKB-1 = edge scatter into bucket runs;
// blocks NCHUNKB.. = dense GEMM h1 = relu(X@W0)@W1 (bf16 MFMA).
// B fragments from FRAGMENT-PACKED W0P/W1P in global: contiguous coalesced
// 1KB wave-loads. No weight LDS, no barriers in the GEMM branch; LDS is only
// the 17.4KB h0s relay.
// ---------------------------------------------------------------------------
__global__ __launch_bounds__(256, 4)
void k_scatter_gemm(const int* __restrict__ dst, const int* __restrict__ src,
                    const float* __restrict__ val, const int* __restrict__ bbase,
                    const int* __restrict__ my_base, int2* __restrict__ bsv,
                    const float* __restrict__ feat, const __bf16* __restrict__ W0P,
                    const __bf16* __restrict__ W1P, __bf16* __restrict__ h1b) {
  __shared__ __align__(16) char smem[64 * HPAD * 2];   // 17,408 B
  const int tid = threadIdx.x;

  if (blockIdx.x < NCHUNKB) {
    // ---------------- scatter branch ----------------
    int* cur = (int*)smem;
    cur[tid] = bbase[tid] + my_base[blockIdx.x * NBUCK + tid];
    __syncthreads();
    const int base = blockIdx.x * CHUNK;
#pragma unroll
    for (int j = 0; j < CHUNK / 1024; ++j) {
      const int e = base + (j * 256 + tid) * 4;
      if (e < NEDGES) {
        const int4   d  = *(const int4*)&dst[e];
        const int4   sc = *(const int4*)&src[e];
        const float4 vv = *(const float4*)&val[e];
        int p, b, ld;
        b = (unsigned)d.x / NPB; ld = d.x - b * NPB;
        p = atomicAdd(&cur[b], 1);
        bsv[p] = make_int2(sc.x | (ld << 17), __float_as_int(vv.x));
        b = (unsigned)d.y / NPB; ld = d.y - b * NPB;
        p = atomicAdd(&cur[b], 1);
        bsv[p] = make_int2(sc.y | (ld << 17), __float_as_int(vv.y));
        b = (unsigned)d.z / NPB; ld = d.z - b * NPB;
        p = atomicAdd(&cur[b], 1);
        bsv[p] = make_int2(sc.z | (ld << 17), __float_as_int(vv.z));
        b = (unsigned)d.w / NPB; ld = d.w - b * NPB;
        p = atomicAdd(&cur[b], 1);
        bsv[p] = make_int2(sc.w | (ld << 17), __float_as_int(vv.w));
      }
    }
    return;
  }

  // ---------------- gemm branch (4 waves, 64 rows) ----------------
  __bf16* h0s = (__bf16*)smem;                 // [64][HPAD] per-wave stripes

  const int wave = tid >> 6;
  const int lane = tid & 63;
  const int q    = lane >> 4;
  const int l16  = lane & 15;
  const int rb   = (blockIdx.x - NCHUNKB) * 64;

  int row = rb + wave * 16 + l16;
  if (row >= NNODES) row = NNODES - 1;          // clamped loads; stores guarded
  const float* __restrict__ arow = feat + (size_t)row * INDIM;

  f32x4 acc[8];
#pragma unroll
  for (int t = 0; t < 8; ++t) acc[t] = (f32x4){0.f, 0.f, 0.f, 0.f};

#pragma unroll 4
  for (int kk = 0; kk < INDIM / 32; ++kk) {
    const int k0 = kk * 32;
    const float4 a0 = *(const float4*)&arow[k0 + q * 8];
    const float4 a1 = *(const float4*)&arow[k0 + q * 8 + 4];
    bf16x8 aF;
    aF[0] = (__bf16)a0.x; aF[1] = (__bf16)a0.y; aF[2] = (__bf16)a0.z; aF[3] = (__bf16)a0.w;
    aF[4] = (__bf16)a1.x; aF[5] = (__bf16)a1.y; aF[6] = (__bf16)a1.z; aF[7] = (__bf16)a1.w;
#pragma unroll
    for (int t = 0; t < 8; ++t) {
      const bf16x8 bF = *(const bf16x8*)&W0P[(size_t)(((kk * 8 + t) * 64 + lane) * 8)];
      acc[t] = __builtin_amdgcn_mfma_f32_16x16x32_bf16(aF, bF, acc[t], 0, 0, 0);
    }
  }

  // ReLU + cvt -> h0s in A-operand layout (C/D: row=q*4+j, col=l16).
  // No barriers: each wave writes and reads only its own 16-row stripe.
#pragma unroll
  for (int t = 0; t < 8; ++t) {
#pragma unroll
    for (int j = 0; j < 4; ++j) {
      float v = acc[t][j];
      v = v > 0.f ? v : 0.f;
      h0s[(wave * 16 + q * 4 + j) * HPAD + t * 16 + l16] = (__bf16)v;
    }
  }

  f32x4 acc2[4];
#pragma unroll
  for (int t = 0; t < 4; ++t) acc2[t] = (f32x4){0.f, 0.f, 0.f, 0.f};
#pragma unroll
  for (int kk = 0; kk < HID / 32; ++kk) {
    const bf16x8 aF = *(const bf16x8*)&h0s[(wave * 16 + l16) * HPAD + kk * 32 + q * 8];
#pragma unroll
    for (int t = 0; t < 4; ++t) {
      const bf16x8 bF = *(const bf16x8*)&W1P[(size_t)(((kk * 4 + t) * 64 + lane) * 8)];
      acc2[t] = __builtin_amdgcn_mfma_f32_16x16x32_bf16(aF, bF, acc2[t], 0, 0, 0);
    }
  }

#pragma unroll
  for (int t = 0; t < 4; ++t) {
#pragma unroll
    for (int j = 0; j < 4; ++j) {
      const int grow = rb + wave * 16 + q * 4 + j;
      if (grow < NNODES)
        h1b[(size_t)grow * NCLS + t * 16 + l16] = (__bf16)acc2[t][j];
    }
  }
}

// ---------------------------------------------------------------------------
// Per-bucket CSR fill, 512 threads: degree histogram + padded scan (pad to 8)
// in LDS, rowinfo[w] = {base, pdeg}; writes confined to 128KB region/block.
// ---------------------------------------------------------------------------
__global__ __launch_bounds__(512)
void kB3(const int2* __restrict__ bsv, const int* __restrict__ bbase,
         int2* __restrict__ rowinfo, int2* __restrict__ ecsr) {
  __shared__ int dl[512];
  __shared__ int cur[NPB];
  __shared__ int s[512];
  const int t = threadIdx.x;
  const int b = blockIdx.x;
  const int nb = b * NPB;
  dl[t] = 0;
  __syncthreads();
  const int beg = bbase[b], end = bbase[b + 1];
  for (int e = beg + t; e < end; e += 512)
    atomicAdd(&dl[((unsigned)bsv[e].x) >> 17], 1);
  __syncthreads();
  const int d = (t < NPB) ? dl[t] : 0;
  const int pd = (d + 7) & ~7;
  s[t] = pd;
  __syncthreads();
  for (int off = 1; off < 512; off <<= 1) {
    int x = (t >= off) ? s[t - off] : 0;
    __syncthreads();
    s[t] += x;
    __syncthreads();
  }
  const int excl = s[t] - pd;
  const int gb = b * BCAP;
  const int2 z2 = make_int2(0, 0);
  if (t < NPB) {
    const int c = gb + excl;
    cur[t] = c;
    if (nb + t < NNODES) rowinfo[nb + t] = make_int2(c, pd);
    for (int k = d; k < pd; ++k) ecsr[c + k] = z2;    // zero padding entries
  }
  __syncthreads();
  for (int e = beg + t; e < end; e += 512) {
    const int2 sv = bsv[e];
    const int ld = ((unsigned)sv.x) >> 17;
    const int p = atomicAdd(&cur[ld], 1);             // LDS atomic
    ecsr[p] = make_int2(sv.x & 0x1FFFF, sv.y);
  }
}

// ---------------------------------------------------------------------------
// SpMM gather, 4 rows per wave / 4 cols per lane (8B bf16x4 gathers).
// lane = g*16+l16: row = wid*4+g, cols = l16*4..+3. Each gather instruction
// moves 4 cache lines (one per row-group) vs 1 in the 1-row/wave version:
// 4x fewer vmem instructions per edge. Metadata int4 loads are per-group
// broadcasts (4 lines/instr). Stores: contiguous 1KB (f32) / 512B (bf16)
// per wave. Loop runs to max pdeg of the 4 rows (~+20% iters, exec-masked).
// ---------------------------------------------------------------------------
template <typename OUT_T>
__global__ __launch_bounds__(256, 4)
void k_spmm(const int2* __restrict__ rowinfo, const int2* __restrict__ ecsr,
            const __bf16* __restrict__ x, OUT_T* __restrict__ y) {
  const int wid  = (blockIdx.x * 256 + threadIdx.x) >> 6;  // 25000 waves
  const int lane = threadIdx.x & 63;
  const int g    = lane >> 4;                              // row group 0..3
  const int l16  = lane & 15;
  const int row  = wid * 4 + g;                            // < NNODES (exact)
  const int c0   = l16 * 4;
  const int2 ri  = rowinfo[row];                           // {base, pdeg}
  const int base = ri.x, pdeg = ri.y;
  f32x4 acc = (f32x4){0.f, 0.f, 0.f, 0.f};
  for (int j = 0; j < pdeg; j += 8) {
    const int4 m0 = *(const int4*)&ecsr[base + j];
    const int4 m1 = *(const int4*)&ecsr[base + j + 2];
    const int4 m2 = *(const int4*)&ecsr[base + j + 4];
    const int4 m3 = *(const int4*)&ecsr[base + j + 6];
    const bf16x4 x0 = *(const bf16x4*)&x[(size_t)m0.x * NCLS + c0];
    const bf16x4 x1 = *(const bf16x4*)&x[(size_t)m0.z * NCLS + c0];
    const bf16x4 x2 = *(const bf16x4*)&x[(size_t)m1.x * NCLS + c0];
    const bf16x4 x3 = *(const bf16x4*)&x[(size_t)m1.z * NCLS + c0];
    const bf16x4 x4 = *(const bf16x4*)&x[(size_t)m2.x * NCLS + c0];
    const bf16x4 x5 = *(const bf16x4*)&x[(size_t)m2.z * NCLS + c0];
    const bf16x4 x6 = *(const bf16x4*)&x[(size_t)m3.x * NCLS + c0];
    const bf16x4 x7 = *(const bf16x4*)&x[(size_t)m3.z * NCLS + c0];
    const float v0 = __int_as_float(m0.y), v1 = __int_as_float(m0.w);
    const float v2 = __int_as_float(m1.y), v3 = __int_as_float(m1.w);
    const float v4 = __int_as_float(m2.y), v5 = __int_as_float(m2.w);
    const float v6 = __int_as_float(m3.y), v7 = __int_as_float(m3.w);
#pragma unroll
    for (int i = 0; i < 4; ++i) {
      acc[i] += v0 * (float)x0[i];
      acc[i] += v1 * (float)x1[i];
      acc[i] += v2 * (float)x2[i];
      acc[i] += v3 * (float)x3[i];
      acc[i] += v4 * (float)x4[i];
      acc[i] += v5 * (float)x5[i];
      acc[i] += v6 * (float)x6[i];
      acc[i] += v7 * (float)x7[i];
    }
  }
  if constexpr (sizeof(OUT_T) == 4) {
    float4 o;
    o.x = acc[0]; o.y = acc[1]; o.z = acc[2]; o.w = acc[3];
    *(float4*)&y[(size_t)row * NCLS + c0] = o;
  } else {
    bf16x4 o;
    o[0] = (__bf16)acc[0]; o[1] = (__bf16)acc[1];
    o[2] = (__bf16)acc[2]; o[3] = (__bf16)acc[3];
    *(bf16x4*)&y[(size_t)row * NCLS + c0] = o;
  }
}

// ---------------------------------------------------------------------------
extern "C" void kernel_launch(void* const* d_in, const int* in_sizes, int n_in,
                              void* d_out, int out_size, void* d_ws, size_t ws_size,
                              hipStream_t stream) {
  const float* feat = (const float*)d_in[0];
  const float* W0   = (const float*)d_in[1];
  const float* W1   = (const float*)d_in[2];
  const float* eval = (const float*)d_in[3];
  const int*   esrc = (const int*)d_in[4];
  const int*   edst = (const int*)d_in[5];
  float* out = (float*)d_out;

  // Workspace (~60.1 MB). bsv lives in d_out (exactly NEDGES int2 = 25.6 MB,
  // dead after kB3; final spmm overwrites d_out). my_base aliases h2b
  // (disjoint lifetimes: my_base dead after k_scatter_gemm; h2b first
  // written by spmm layer 1).
  char* p = (char*)d_ws;
  int2*   ecsr    = (int2*)p;   p += (size_t)NBUCK * BCAP * 8;  // 33,554,432
  int2*   rowinfo = (int2*)p;   p += (size_t)NCAP * 8;          // 800,768
  int*    gcnt    = (int*)p;    p += 1024;
  int*    bbase   = (int*)p;    p += 2048;
  __bf16* W0P     = (__bf16*)p; p += 131072;
  __bf16* W1P     = (__bf16*)p; p += 16384;
  __bf16* h1b     = (__bf16*)p; p += 12800000;
  __bf16* h2b     = (__bf16*)p; p += 12800000;
  int*    my_base = (int*)h2b;                                  // 800,768 alias
  int2*   bsv     = (int2*)d_out;                               // 25,600,000

  hipMemsetAsync(gcnt, 0, NBUCK * sizeof(int), stream);
  k_count_wcvt <<<NCHUNKB + 1, 256, 0, stream>>>(edst, gcnt, my_base,
                                                 W0, W1, W0P, W1P);
  kA_bscan     <<<1, 256, 0, stream>>>(gcnt, bbase);
  k_scatter_gemm<<<NCHUNKB + (NNODES + 63) / 64, 256, 0, stream>>>(
      edst, esrc, eval, bbase, my_base, bsv, feat, W0P, W1P, h1b);
  kB3          <<<NBUCK, 512, 0, stream>>>(bsv, bbase, rowinfo, ecsr);

  k_spmm<__bf16><<<NNODES / 16, 256, 0, stream>>>(rowinfo, ecsr, h1b, h2b);
  k_spmm<float> <<<NNODES / 16, 256, 0, stream>>>(rowinfo, ecsr, h2b, out);

  (void)in_sizes; (void)n_in; (void)out_size; (void)ws_size;
}

// Round 6
// 569.844 us; speedup vs baseline: 1.0661x; 1.0083x over previous
//
#include <hip/hip_runtime.h>
#include <hip/hip_bf16.h>

// Problem constants (match reference)
#define NNODES 100000
#define NEDGES 3200000
#define INDIM  512
#define HID    128
#define NCLS   64

// Bucketed CSR build
#define NBUCK  256
#define NPB    391                         // nodes per bucket; 256*391 = 100096
#define NCAP   (NBUCK * NPB)               // 100096
#define BCAP   16384                       // fixed padded capacity per bucket
#define CHUNK  4096                        // 782 scatter blocks
#define NCHUNKB ((NEDGES + CHUNK - 1) / CHUNK)   // 782 blocks

typedef __bf16 bf16x8 __attribute__((ext_vector_type(8)));
typedef __bf16 bf16x4 __attribute__((ext_vector_type(4)));
typedef float  f32x4  __attribute__((ext_vector_type(4)));

#define HPAD 136   // h0s row pad (272B stride; 68 words %32=4)

// ---------------------------------------------------------------------------
// Fused: blocks 0..NCHUNKB-1 = per-chunk bucket histogram (reserve runs);
//        block NCHUNKB      = weight conversion into MFMA-FRAGMENT-PACKED order.
// W0P[((kk*8+t)*64+lane)*8 + j] = W0[(kk*32+(lane>>4)*8+j)*HID + t*16+(lane&15)]
// => each B-fragment load in the GEMM is a fully-coalesced contiguous 1KB
//    wave-load (16B/lane), per-kk working set 8KB.
// ---------------------------------------------------------------------------
__global__ __launch_bounds__(256)
void k_count_wcvt(const int* __restrict__ dst, int* __restrict__ gcnt,
                  int* __restrict__ my_base,
                  const float* __restrict__ W0, const float* __restrict__ W1,
                  __bf16* __restrict__ W0P, __bf16* __restrict__ W1P) {
  const int t = threadIdx.x;
  if (blockIdx.x == NCHUNKB) {
    for (int i = t; i < 65536; i += 256) {      // W0 [512][128] -> packed
      const int c = i >> 3, j = i & 7;
      const int ln = c & 63, tt = (c >> 6) & 7, kk = c >> 9;
      const int row = tt * 16 + (ln & 15);
      const int k   = kk * 32 + (ln >> 4) * 8 + j;
      W0P[i] = (__bf16)W0[k * HID + row];
    }
    for (int i = t; i < 8192; i += 256) {       // W1 [128][64] -> packed
      const int c = i >> 3, j = i & 7;
      const int ln = c & 63, tt = (c >> 6) & 3, kk = c >> 8;
      const int row = tt * 16 + (ln & 15);
      const int k   = kk * 32 + (ln >> 4) * 8 + j;
      W1P[i] = (__bf16)W1[k * NCLS + row];
    }
    return;
  }
  __shared__ int cnt[NBUCK];
  cnt[t] = 0;
  __syncthreads();
  const int base = blockIdx.x * CHUNK;
#pragma unroll
  for (int j = 0; j < CHUNK / 1024; ++j) {
    const int e = base + (j * 256 + t) * 4;
    if (e < NEDGES) {                           // NEDGES%4==0 => full int4 ok
      const int4 d = *(const int4*)&dst[e];
      atomicAdd(&cnt[(unsigned)d.x / NPB], 1);
      atomicAdd(&cnt[(unsigned)d.y / NPB], 1);
      atomicAdd(&cnt[(unsigned)d.z / NPB], 1);
      atomicAdd(&cnt[(unsigned)d.w / NPB], 1);
    }
  }
  __syncthreads();
  my_base[blockIdx.x * NBUCK + t] = atomicAdd(&gcnt[t], cnt[t]);
}

// ---------------------------------------------------------------------------
// Exclusive scan of bucket totals -> bsv segment bases.
// ---------------------------------------------------------------------------
__global__ void kA_bscan(const int* __restrict__ gcnt, int* __restrict__ bbase) {
  __shared__ int s[256];
  const int t = threadIdx.x;
  const int v = gcnt[t];
  s[t] = v;
  __syncthreads();
  for (int off = 1; off < 256; off <<= 1) {
    int x = (t >= off) ? s[t - off] : 0;
    __syncthreads();
    s[t] += x;
    __syncthreads();
  }
  bbase[t] = s[t] - v;
  if (t == 255) bbase[256] = s[255];            // == NEDGES
}

// ---------------------------------------------------------------------------
// Fused dispatch: blocks 0..NCHUNKB-1 = edge scatter into bucket runs;
// blocks NCHUNKB.. = dense GEMM h1 = relu(X@W0)@W1 (bf16 MFMA).
// GEMM K-loop uses an explicit depth-2 A-prefetch rotation (pa/qa/na):
// iteration kk issues the float4 loads for kk+2 and consumes loads issued
// at kk-2 -> ~2 iterations of MFMA+B-load work hide the HBM latency that
// previously stalled every iteration (r4/r5: VGPR=40, zero pipelining).
// ---------------------------------------------------------------------------
__global__ __launch_bounds__(256, 4)
void k_scatter_gemm(const int* __restrict__ dst, const int* __restrict__ src,
                    const float* __restrict__ val, const int* __restrict__ bbase,
                    const int* __restrict__ my_base, int2* __restrict__ bsv,
                    const float* __restrict__ feat, const __bf16* __restrict__ W0P,
                    const __bf16* __restrict__ W1P, __bf16* __restrict__ h1b) {
  __shared__ __align__(16) char smem[64 * HPAD * 2];   // 17,408 B
  const int tid = threadIdx.x;

  if (blockIdx.x < NCHUNKB) {
    // ---------------- scatter branch ----------------
    int* cur = (int*)smem;
    cur[tid] = bbase[tid] + my_base[blockIdx.x * NBUCK + tid];
    __syncthreads();
    const int base = blockIdx.x * CHUNK;
#pragma unroll
    for (int j = 0; j < CHUNK / 1024; ++j) {
      const int e = base + (j * 256 + tid) * 4;
      if (e < NEDGES) {
        const int4   d  = *(const int4*)&dst[e];
        const int4   sc = *(const int4*)&src[e];
        const float4 vv = *(const float4*)&val[e];
        int p, b, ld;
        b = (unsigned)d.x / NPB; ld = d.x - b * NPB;
        p = atomicAdd(&cur[b], 1);
        bsv[p] = make_int2(sc.x | (ld << 17), __float_as_int(vv.x));
        b = (unsigned)d.y / NPB; ld = d.y - b * NPB;
        p = atomicAdd(&cur[b], 1);
        bsv[p] = make_int2(sc.y | (ld << 17), __float_as_int(vv.y));
        b = (unsigned)d.z / NPB; ld = d.z - b * NPB;
        p = atomicAdd(&cur[b], 1);
        bsv[p] = make_int2(sc.z | (ld << 17), __float_as_int(vv.z));
        b = (unsigned)d.w / NPB; ld = d.w - b * NPB;
        p = atomicAdd(&cur[b], 1);
        bsv[p] = make_int2(sc.w | (ld << 17), __float_as_int(vv.w));
      }
    }
    return;
  }

  // ---------------- gemm branch (4 waves, 64 rows) ----------------
  __bf16* h0s = (__bf16*)smem;                 // [64][HPAD] per-wave stripes

  const int wave = tid >> 6;
  const int lane = tid & 63;
  const int q    = lane >> 4;
  const int l16  = lane & 15;
  const int rb   = (blockIdx.x - NCHUNKB) * 64;

  int row = rb + wave * 16 + l16;
  if (row >= NNODES) row = NNODES - 1;          // clamped loads; stores guarded
  const float4* __restrict__ arow4 =
      (const float4*)(feat + (size_t)row * INDIM);  // 128 float4 per row

  f32x4 acc[8];
#pragma unroll
  for (int t = 0; t < 8; ++t) acc[t] = (f32x4){0.f, 0.f, 0.f, 0.f};

  // Depth-2 A-prefetch pipeline: pa = a[kk], qa = a[kk+1], na = a[kk+2].
  float4 pa0 = arow4[q * 2],     pa1 = arow4[q * 2 + 1];
  float4 qa0 = arow4[8 + q * 2], qa1 = arow4[8 + q * 2 + 1];

#pragma unroll 2
  for (int kk = 0; kk < INDIM / 32; ++kk) {
    float4 na0 = pa0, na1 = pa1;
    if (kk < INDIM / 32 - 2) {
      na0 = arow4[(kk + 2) * 8 + q * 2];
      na1 = arow4[(kk + 2) * 8 + q * 2 + 1];
    }
    bf16x8 aF;
    aF[0] = (__bf16)pa0.x; aF[1] = (__bf16)pa0.y; aF[2] = (__bf16)pa0.z; aF[3] = (__bf16)pa0.w;
    aF[4] = (__bf16)pa1.x; aF[5] = (__bf16)pa1.y; aF[6] = (__bf16)pa1.z; aF[7] = (__bf16)pa1.w;
#pragma unroll
    for (int t = 0; t < 8; ++t) {
      const bf16x8 bF = *(const bf16x8*)&W0P[(size_t)(((kk * 8 + t) * 64 + lane) * 8)];
      acc[t] = __builtin_amdgcn_mfma_f32_16x16x32_bf16(aF, bF, acc[t], 0, 0, 0);
    }
    pa0 = qa0; pa1 = qa1;
    qa0 = na0; qa1 = na1;
  }

  // ReLU + cvt -> h0s in A-operand layout (C/D: row=q*4+j, col=l16).
  // No barriers: each wave writes and reads only its own 16-row stripe.
#pragma unroll
  for (int t = 0; t < 8; ++t) {
#pragma unroll
    for (int j = 0; j < 4; ++j) {
      float v = acc[t][j];
      v = v > 0.f ? v : 0.f;
      h0s[(wave * 16 + q * 4 + j) * HPAD + t * 16 + l16] = (__bf16)v;
    }
  }

  f32x4 acc2[4];
#pragma unroll
  for (int t = 0; t < 4; ++t) acc2[t] = (f32x4){0.f, 0.f, 0.f, 0.f};
#pragma unroll
  for (int kk = 0; kk < HID / 32; ++kk) {
    const bf16x8 aF = *(const bf16x8*)&h0s[(wave * 16 + l16) * HPAD + kk * 32 + q * 8];
#pragma unroll
    for (int t = 0; t < 4; ++t) {
      const bf16x8 bF = *(const bf16x8*)&W1P[(size_t)(((kk * 4 + t) * 64 + lane) * 8)];
      acc2[t] = __builtin_amdgcn_mfma_f32_16x16x32_bf16(aF, bF, acc2[t], 0, 0, 0);
    }
  }

#pragma unroll
  for (int t = 0; t < 4; ++t) {
#pragma unroll
    for (int j = 0; j < 4; ++j) {
      const int grow = rb + wave * 16 + q * 4 + j;
      if (grow < NNODES)
        h1b[(size_t)grow * NCLS + t * 16 + l16] = (__bf16)acc2[t][j];
    }
  }
}

// ---------------------------------------------------------------------------
// Per-bucket CSR fill, 1024 threads (1 block/CU is forced by the 256-block
// grid, so block width is the only occupancy lever: 16 waves/CU for the
// latency-bound histogram & placement phases). Scan confined to t<512.
// ---------------------------------------------------------------------------
__global__ __launch_bounds__(1024)
void kB3(const int2* __restrict__ bsv, const int* __restrict__ bbase,
         int2* __restrict__ rowinfo, int2* __restrict__ ecsr) {
  __shared__ int dl[NPB];
  __shared__ int cur[NPB];
  __shared__ int s[512];
  const int t = threadIdx.x;
  const int b = blockIdx.x;
  const int nb = b * NPB;
  for (int i = t; i < NPB; i += 1024) dl[i] = 0;
  __syncthreads();
  const int beg = bbase[b], end = bbase[b + 1];
  for (int e = beg + t; e < end; e += 1024)
    atomicAdd(&dl[((unsigned)bsv[e].x) >> 17], 1);
  __syncthreads();
  int d = 0, pd = 0;
  if (t < 512) {
    d  = (t < NPB) ? dl[t] : 0;
    pd = (d + 7) & ~7;
    s[t] = pd;
  }
  __syncthreads();
  for (int off = 1; off < 512; off <<= 1) {
    int x = 0;
    if (t < 512 && t >= off) x = s[t - off];
    __syncthreads();
    if (t < 512) s[t] += x;
    __syncthreads();
  }
  const int gb = b * BCAP;
  const int2 z2 = make_int2(0, 0);
  if (t < NPB) {
    const int excl = s[t] - pd;
    const int c = gb + excl;
    cur[t] = c;
    if (nb + t < NNODES) rowinfo[nb + t] = make_int2(c, pd);
    for (int k = d; k < pd; ++k) ecsr[c + k] = z2;    // zero padding entries
  }
  __syncthreads();
  for (int e = beg + t; e < end; e += 1024) {
    const int2 sv = bsv[e];
    const int ld = ((unsigned)sv.x) >> 17;
    const int p = atomicAdd(&cur[ld], 1);             // LDS atomic
    ecsr[p] = make_int2(sv.x & 0x1FFFF, sv.y);
  }
}

// ---------------------------------------------------------------------------
// SpMM gather, 4 rows per wave / 4 cols per lane (8B bf16x4 gathers).
// Each gather instruction moves 4 cache lines (one per row-group):
// 4x fewer vmem instructions per edge than 1-row/wave. Stores contiguous.
// ---------------------------------------------------------------------------
template <typename OUT_T>
__global__ __launch_bounds__(256, 4)
void k_spmm(const int2* __restrict__ rowinfo, const int2* __restrict__ ecsr,
            const __bf16* __restrict__ x, OUT_T* __restrict__ y) {
  const int wid  = (blockIdx.x * 256 + threadIdx.x) >> 6;  // 25000 waves
  const int lane = threadIdx.x & 63;
  const int g    = lane >> 4;                              // row group 0..3
  const int l16  = lane & 15;
  const int row  = wid * 4 + g;                            // < NNODES (exact)
  const int c0   = l16 * 4;
  const int2 ri  = rowinfo[row];                           // {base, pdeg}
  const int base = ri.x, pdeg = ri.y;
  f32x4 acc = (f32x4){0.f, 0.f, 0.f, 0.f};
  for (int j = 0; j < pdeg; j += 8) {
    const int4 m0 = *(const int4*)&ecsr[base + j];
    const int4 m1 = *(const int4*)&ecsr[base + j + 2];
    const int4 m2 = *(const int4*)&ecsr[base + j + 4];
    const int4 m3 = *(const int4*)&ecsr[base + j + 6];
    const bf16x4 x0 = *(const bf16x4*)&x[(size_t)m0.x * NCLS + c0];
    const bf16x4 x1 = *(const bf16x4*)&x[(size_t)m0.z * NCLS + c0];
    const bf16x4 x2 = *(const bf16x4*)&x[(size_t)m1.x * NCLS + c0];
    const bf16x4 x3 = *(const bf16x4*)&x[(size_t)m1.z * NCLS + c0];
    const bf16x4 x4 = *(const bf16x4*)&x[(size_t)m2.x * NCLS + c0];
    const bf16x4 x5 = *(const bf16x4*)&x[(size_t)m2.z * NCLS + c0];
    const bf16x4 x6 = *(const bf16x4*)&x[(size_t)m3.x * NCLS + c0];
    const bf16x4 x7 = *(const bf16x4*)&x[(size_t)m3.z * NCLS + c0];
    const float v0 = __int_as_float(m0.y), v1 = __int_as_float(m0.w);
    const float v2 = __int_as_float(m1.y), v3 = __int_as_float(m1.w);
    const float v4 = __int_as_float(m2.y), v5 = __int_as_float(m2.w);
    const float v6 = __int_as_float(m3.y), v7 = __int_as_float(m3.w);
#pragma unroll
    for (int i = 0; i < 4; ++i) {
      acc[i] += v0 * (float)x0[i];
      acc[i] += v1 * (float)x1[i];
      acc[i] += v2 * (float)x2[i];
      acc[i] += v3 * (float)x3[i];
      acc[i] += v4 * (float)x4[i];
      acc[i] += v5 * (float)x5[i];
      acc[i] += v6 * (float)x6[i];
      acc[i] += v7 * (float)x7[i];
    }
  }
  if constexpr (sizeof(OUT_T) == 4) {
    float4 o;
    o.x = acc[0]; o.y = acc[1]; o.z = acc[2]; o.w = acc[3];
    *(float4*)&y[(size_t)row * NCLS + c0] = o;
  } else {
    bf16x4 o;
    o[0] = (__bf16)acc[0]; o[1] = (__bf16)acc[1];
    o[2] = (__bf16)acc[2]; o[3] = (__bf16)acc[3];
    *(bf16x4*)&y[(size_t)row * NCLS + c0] = o;
  }
}

// ---------------------------------------------------------------------------
extern "C" void kernel_launch(void* const* d_in, const int* in_sizes, int n_in,
                              void* d_out, int out_size, void* d_ws, size_t ws_size,
                              hipStream_t stream) {
  const float* feat = (const float*)d_in[0];
  const float* W0   = (const float*)d_in[1];
  const float* W1   = (const float*)d_in[2];
  const float* eval = (const float*)d_in[3];
  const int*   esrc = (const int*)d_in[4];
  const int*   edst = (const int*)d_in[5];
  float* out = (float*)d_out;

  // Workspace (~60.1 MB). bsv lives in d_out (exactly NEDGES int2 = 25.6 MB,
  // dead after kB3; final spmm overwrites d_out). my_base aliases h2b
  // (disjoint lifetimes: my_base dead after k_scatter_gemm; h2b first
  // written by spmm layer 1).
  char* p = (char*)d_ws;
  int2*   ecsr    = (int2*)p;   p += (size_t)NBUCK * BCAP * 8;  // 33,554,432
  int2*   rowinfo = (int2*)p;   p += (size_t)NCAP * 8;          // 800,768
  int*    gcnt    = (int*)p;    p += 1024;
  int*    bbase   = (int*)p;    p += 2048;
  __bf16* W0P     = (__bf16*)p; p += 131072;
  __bf16* W1P     = (__bf16*)p; p += 16384;
  __bf16* h1b     = (__bf16*)p; p += 12800000;
  __bf16* h2b     = (__bf16*)p; p += 12800000;
  int*    my_base = (int*)h2b;                                  // 800,768 alias
  int2*   bsv     = (int2*)d_out;                               // 25,600,000

  hipMemsetAsync(gcnt, 0, NBUCK * sizeof(int), stream);
  k_count_wcvt <<<NCHUNKB + 1, 256, 0, stream>>>(edst, gcnt, my_base,
                                                 W0, W1, W0P, W1P);
  kA_bscan     <<<1, 256, 0, stream>>>(gcnt, bbase);
  k_scatter_gemm<<<NCHUNKB + (NNODES + 63) / 64, 256, 0, stream>>>(
      edst, esrc, eval, bbase, my_base, bsv, feat, W0P, W1P, h1b);
  kB3          <<<NBUCK, 1024, 0, stream>>>(bsv, bbase, rowinfo, ecsr);

  k_spmm<__bf16><<<NNODES / 16, 256, 0, stream>>>(rowinfo, ecsr, h1b, h2b);
  k_spmm<float> <<<NNODES / 16, 256, 0, stream>>>(rowinfo, ecsr, h2b, out);

  (void)in_sizes; (void)n_in; (void)out_size; (void)ws_size;
}